// Round 8
// baseline (266.655 us; speedup 1.0000x reference)
//
#include <hip/hip_runtime.h>

// ComplexMixture: B=32, S=8192, D=64, fp32 in/out.
// out_real = (R^T R + I^T I)/S   [B,64,64]  (symmetric)
// out_imag = (R^T I - (R^T I)^T)/S          (antisymmetric)
// R10: no-LDS main loop. Fragments loaded DIRECTLY from global in MFMA
//      layout (lane l reads M[s0+(l>>5)*8+j][d0+(l&31)] -> 2x128B segments
//      per instr, coalesced). Zero barriers/LDS in loop: waves free-run
//      (copy-kernel-style latency hiding), depth-2 fragment ring,
//      16 waves/CU. Atomic-output epilogue (LDS scratch only there).

#define BATCH  32
#define SEQ    8192
#define DD     64
#define CHUNKS 32
#define SCHUNK (SEQ / CHUNKS)   // 256 rows per block
#define KST    (SCHUNK / 16)    // 16 k-steps of 16

typedef __bf16 bf16x8 __attribute__((ext_vector_type(8)));
typedef float  f32x16 __attribute__((ext_vector_type(16)));

__device__ __forceinline__ unsigned bf16pk(float a, float b) {
  unsigned ua = __builtin_bit_cast(unsigned, a);
  unsigned ub = __builtin_bit_cast(unsigned, b);
  ua = (ua + 0x7fffu + ((ua >> 16) & 1u)) >> 16;   // RNE to bf16
  ub = (ub + 0x7fffu + ((ub >> 16) & 1u)) >> 16;
  return (ua & 0xffffu) | (ub << 16);
}

__device__ __forceinline__ void atomAdd(float* p, float v) {
  __hip_atomic_fetch_add(p, v, __ATOMIC_RELAXED, __HIP_MEMORY_SCOPE_AGENT);
}

__global__ __launch_bounds__(256, 4) void gram_fused(
    const float* __restrict__ R, const float* __restrict__ I,
    float* __restrict__ out)
{
  __shared__ float sc[64 * 65];          // epilogue scratch only (16.6 KB)
  const int tid  = threadIdx.x;
  const int wave = tid >> 6;
  const int lane = tid & 63;
  const int l31  = lane & 31;
  const int lhi  = lane >> 5;
  const int b = blockIdx.x & 31;
  const int c = blockIdx.x >> 5;
  const int m0 = (wave >> 1) * 32;       // output quadrant of this wave
  const int n0 = (wave & 1) * 32;
  // uniform bases (SGPR) + small per-lane offsets (VGPR)
  const float* RbC = R + (size_t)b * (SEQ * DD) + (size_t)c * SCHUNK * DD;
  const float* IbC = I + (size_t)b * (SEQ * DD) + (size_t)c * SCHUNK * DD;
  const int offA = lhi * 8 * DD + m0 + l31;   // lane offset for A-frag column
  const int offB = lhi * 8 * DD + n0 + l31;   // lane offset for B-frag column

  f32x16 accR = {};   // rr + ii quadrant (m0,n0)
  f32x16 accI = {};   // ri quadrant (m0,n0)

  // depth-2 staging ring: 64 f32 regs
  float ar[2][8], br[2][8], ai[2][8], bi[2][8];

  // issue the 32-dword fragment burst for k-step t_ into ring slot rs_
#define LOADF(t_, rs_) do { \
    const float* pR_ = RbC + (t_) * (16 * DD); \
    const float* pI_ = IbC + (t_) * (16 * DD); \
    _Pragma("unroll") \
    for (int j = 0; j < 8; ++j) { \
      ar[rs_][j] = pR_[offA + j * DD]; br[rs_][j] = pR_[offB + j * DD]; \
      ai[rs_][j] = pI_[offA + j * DD]; bi[rs_][j] = pI_[offB + j * DD]; \
    } \
    asm volatile("" ::: "memory"); \
  } while (0)

#define CONV(rs_, fa_, arr_) do { \
    uint4 u_; \
    u_.x = bf16pk(arr_[rs_][0], arr_[rs_][1]); \
    u_.y = bf16pk(arr_[rs_][2], arr_[rs_][3]); \
    u_.z = bf16pk(arr_[rs_][4], arr_[rs_][5]); \
    u_.w = bf16pk(arr_[rs_][6], arr_[rs_][7]); \
    fa_ = __builtin_bit_cast(bf16x8, u_); \
  } while (0)

  // prologue: 2 fragment bursts in flight
  LOADF(0, 0);
  LOADF(1, 1);

  #pragma unroll
  for (int t = 0; t < KST; ++t) {
    const int rs = t & 1;
    bf16x8 faR, fbR, faI, fbI;
    CONV(rs, faR, ar); CONV(rs, fbR, br);   // vmcnt waits only on burst t
    CONV(rs, faI, ai); CONV(rs, fbI, bi);   // (burst t+1 stays outstanding)
    if (t + 2 < KST) LOADF(t + 2, rs);      // refill ring slot just freed
    accR = __builtin_amdgcn_mfma_f32_32x32x16_bf16(faR, fbR, accR, 0, 0, 0);
    accR = __builtin_amdgcn_mfma_f32_32x32x16_bf16(faI, fbI, accR, 0, 0, 0);
    accI = __builtin_amdgcn_mfma_f32_32x32x16_bf16(faR, fbI, accI, 0, 0, 0);
  }
#undef LOADF
#undef CONV

  // ---- epilogue: atomic-accumulate scaled partials into out ----
  const float inv = 1.0f / (float)SEQ;
  float* outR = out + (size_t)b * 4096;
  float* outM = out + 131072 + (size_t)b * 4096;
  const int jj = n0 + l31;

  // real: direct from regs (full 64x64 covered by the 4 quadrants)
  #pragma unroll
  for (int r = 0; r < 16; ++r) {
    const int i = m0 + (r & 3) + 8 * (r >> 2) + 4 * lhi;
    atomAdd(&outR[i * 64 + jj], accR[r] * inv);
  }

  // imag: antisymmetrize via LDS scratch, then atomics.
  #pragma unroll
  for (int r = 0; r < 16; ++r) {
    const int i = m0 + (r & 3) + 8 * (r >> 2) + 4 * lhi;
    sc[i * 65 + jj] = accI[r];
  }
  __syncthreads();
  #pragma unroll
  for (int r = 0; r < 16; ++r) {
    const int i = m0 + (r & 3) + 8 * (r >> 2) + 4 * lhi;
    const float m = (sc[i * 65 + jj] - sc[jj * 65 + i]) * inv;
    atomAdd(&outM[i * 64 + jj], m);
  }
}

extern "C" void kernel_launch(void* const* d_in, const int* in_sizes, int n_in,
                              void* d_out, int out_size, void* d_ws, size_t ws_size,
                              hipStream_t stream) {
  const float* R = (const float*)d_in[0];
  const float* I = (const float*)d_in[1];
  float* out = (float*)d_out;
  (void)d_ws; (void)ws_size;

  hipMemsetAsync(d_out, 0, (size_t)out_size, stream);   // capture-safe
  gram_fused<<<BATCH * CHUNKS, 256, 0, stream>>>(R, I, out);
}